// Round 8
// baseline (264.058 us; speedup 1.0000x reference)
//
#include <hip/hip_runtime.h>
#include <math.h>

#define DD 64
#define WSTR 68          // weight-row LDS stride: 16B-aligned, even bank spread
#define NEG_SLOPE 0.2f
#define SCALING 0.125f   // 1/sqrt(64)
#define CAP 64           // fixed per-node edge capacity; deg~Bin(1.25M,1/50k), P(>64)~3e-15
#define PART 8           // XCD partitions
#define CAPB 128         // per-chunk per-partition LDS staging capacity (mean 32)

__device__ __forceinline__ float lrelu(float x) { return x >= 0.0f ? x : NEG_SLOPE * x; }

__device__ __forceinline__ unsigned bf16_rne(float f) {   // round-to-nearest-even bf16 bits
    unsigned u = __float_as_uint(f);
    u += 0x7FFFu + ((u >> 16) & 1u);
    return u >> 16;
}

__device__ __forceinline__ float bfly_sum64(float v) {
    #pragma unroll
    for (int off = 1; off < 64; off <<= 1) v += __shfl_xor(v, off);
    return v;
}

// ---- K1: fused prep (wave0 folds Watt/a -> v1,v2,c1,c2) + per-node attention
//          scalars + bf16 feature cast + cnt=0 + gcur=0. No W1 GEMM (linearity:
//          applied once per node in gather).
__global__ __launch_bounds__(256) void k_node1(
        const float* __restrict__ feat, const float* __restrict__ Watt,
        const float* __restrict__ Wattb, const float* __restrict__ a,
        float* __restrict__ s_src, float* __restrict__ s_dst,
        unsigned* __restrict__ feat16, int* __restrict__ cnt,
        int* __restrict__ gcur, int N) {
    __shared__ float v1s[DD], v2s[DD], csh[2];
    int t = threadIdx.x;
    if (blockIdx.x == 0 && t < PART) gcur[t] = 0;
    if (t < 64) {                             // wave 0 recomputes the tiny fold
        float s1 = 0.f, s2 = 0.f;
        for (int d = 0; d < DD; ++d) {
            float w = Watt[d * DD + t];
            s1 = fmaf(w, a[d], s1);
            s2 = fmaf(w, a[DD + d], s2);
        }
        v1s[t] = s1; v2s[t] = s2;
        float b = Wattb[t];
        float p1 = bfly_sum64(b * a[t]);
        float p2 = bfly_sum64(b * a[DD + t]);
        if (t == 0) { csh[0] = p1; csh[1] = p2; }
    }
    __syncthreads();
    int lane = t & 63, wslot = t >> 6;
    float v1l = v1s[lane], v2l = v2s[lane], c1 = csh[0], c2 = csh[1];
    int n0 = (blockIdx.x * 4 + wslot) * 4;    // quad of nodes per wave
    if (n0 >= N) return;

    float fd[4], p1[4], p2[4];
    #pragma unroll
    for (int i = 0; i < 4; ++i) {
        int n = n0 + i;
        fd[i] = (n < N) ? feat[n * DD + lane] : 0.f;
        p1[i] = fd[i] * v1l;
        p2[i] = fd[i] * v2l;
    }
    #pragma unroll
    for (int off = 1; off < 64; off <<= 1) {  // 8 interleaved butterfly chains
        #pragma unroll
        for (int i = 0; i < 4; ++i) {
            p1[i] += __shfl_xor(p1[i], off);
            p2[i] += __shfl_xor(p2[i], off);
        }
    }
    #pragma unroll
    for (int i = 0; i < 4; ++i) {
        int n = n0 + i;
        unsigned me = bf16_rne(fd[i]);
        unsigned pair = me | (__shfl_down(me, 1) << 16);  // even lanes: packed (2c,2c+1)
        unsigned v = __shfl(pair, 2 * lane);              // lane c<32 <- lane 2c
        if (n < N) {
            if (lane < 32) feat16[n * 32 + lane] = v;
            if (lane == 0) { s_src[n] = p1[i] + c1; s_dst[n] = p2[i] + c2; cnt[n] = 0; }
        }
    }
}

// ---- K2a: single pass over edges -> 8 per-partition record lists (partition =
//           dst&7). Records (w|src, dst) staged in 8-way LDS bins, flushed with
//           dense coalesced writes; 8 cursor atomics per 256-edge chunk. Spill
//           path (LDS bin overflow) appends directly — correct for any dist.
__global__ __launch_bounds__(256) void k_bucketA(
        const int* __restrict__ src, const int* __restrict__ dst,
        const int* __restrict__ et,
        const float* __restrict__ s_src, const float* __restrict__ s_dst,
        int* __restrict__ gcur, uint2* __restrict__ plist, int pcap, int E) {
    __shared__ uint2 buf[PART][CAPB];
    __shared__ int cnt8[PART], base8[PART];
    int t = threadIdx.x;
    for (long long cbase = (long long)blockIdx.x * 256; cbase < E;
         cbase += (long long)gridDim.x * 256) {
        if (t < PART) cnt8[t] = 0;
        __syncthreads();
        int i = (int)cbase + t;
        if (i < E) {
            int d = dst[i], s = src[i];
            float e = s_src[s] + s_dst[d] + (et[i] == 0 ? 5.0f : 0.0f);
            float w = __expf(lrelu(e * SCALING));
            uint2 rec = make_uint2((bf16_rne(w) << 16) | (unsigned)s, (unsigned)d);
            int p = d & 7;
            int pos = atomicAdd(&cnt8[p], 1);
            if (pos < CAPB) buf[p][pos] = rec;
            else { int g = atomicAdd(&gcur[p], 1); plist[p * pcap + g] = rec; }
        }
        __syncthreads();
        if (t < PART) {
            int nr = cnt8[t]; if (nr > CAPB) nr = CAPB;
            base8[t] = atomicAdd(&gcur[t], nr);
        }
        __syncthreads();
        #pragma unroll
        for (int pp = 0; pp < PART; ++pp) {
            int nr = cnt8[pp]; if (nr > CAPB) nr = CAPB;
            int gb = base8[pp];
            for (int j = t; j < nr; j += 256) plist[pp * pcap + gb + j] = buf[pp][j];
        }
        __syncthreads();
    }
}

// ---- K2b: blocks 8k+p consume partition p (coalesced reads) and scatter into
//           wpack. Each wpack line belongs to one node -> one partition -> one
//           XCD's L2 under round-robin dispatch: stores combine, ~1 writeback
//           per line. Correct under ANY block->XCD mapping (G16-safe).
__global__ __launch_bounds__(256) void k_bucketB(
        const int* __restrict__ gcur, const uint2* __restrict__ plist, int pcap,
        int* __restrict__ cnt, unsigned* __restrict__ wpack) {
    int p = blockIdx.x & 7;
    int M = gcur[p];
    int stride = (gridDim.x >> 3) * 256;
    for (int j = (blockIdx.x >> 3) * 256 + threadIdx.x; j < M; j += stride) {
        uint2 r = plist[p * pcap + j];
        int d = (int)r.y;
        int slot = atomicAdd(&cnt[d], 1);
        if (slot > CAP - 1) slot = CAP - 1;  // never in practice (P ~ 3e-15)
        wpack[(d << 6) + slot] = r.x;
    }
}

// ---- K3: wave per node (grid-strided): g = sum_j w_j*feat[src_j] (half-wave row
//          gather, 2 edges/step, ILP-4), then h_neigh = (W1 g + l b1)/(l+eps) and
//          out = lrelu(f + hn + (f*hn)@W2^T + b2) via two LDS GEMVs.
__global__ __launch_bounds__(256) void k_gather(
        const float* __restrict__ feat, const unsigned* __restrict__ feat16,
        const float* __restrict__ W1, const float* __restrict__ W1b,
        const float* __restrict__ W2, const float* __restrict__ W2b,
        const int* __restrict__ cnt, const unsigned* __restrict__ wpack,
        float* __restrict__ out, int N) {
    __shared__ float W1p[DD * WSTR], W2p[DD * WSTR];
    __shared__ float plds[4][DD];
    int t = threadIdx.x;
    for (int i = t; i < DD * DD; i += 256) {
        int d = i >> 6, k = i & 63;
        W1p[d * WSTR + k] = W1[i];
        W2p[d * WSTR + k] = W2[i];
    }
    __syncthreads();
    int lane = t & 63, wslot = t >> 6;
    int c = lane & 31, h = lane >> 5;        // half-wave id: processes edges tt+h
    float b1l = W1b[lane], b2l = W2b[lane];
    const float4* wrow1 = (const float4*)&W1p[lane * WSTR];
    const float4* wrow2 = (const float4*)&W2p[lane * WSTR];
    float* pl = plds[wslot];
    int wv = blockIdx.x * 4 + wslot;
    int nw = gridDim.x * 4;
    for (int n = wv; n < N; n += nw) {
        int m = cnt[n]; if (m > CAP) m = CAP;
        unsigned u = wpack[(n << 6) + lane]; // whole edge list in one 256B load
        if (lane >= m) u = 0;                // pad: w=0, src=0

        float ax = 0.f, ay = 0.f, bx = 0.f, by = 0.f, l = 0.f;
        int tt = 0;
        for (; tt + 8 <= m; tt += 8) {       // 8 edges in flight (4 per half-wave)
            unsigned e0 = __shfl(u, tt + h);
            unsigned e1 = __shfl(u, tt + 2 + h);
            unsigned e2 = __shfl(u, tt + 4 + h);
            unsigned e3 = __shfl(u, tt + 6 + h);
            unsigned v0 = feat16[(e0 & 0xFFFFu) * 32 + c];
            unsigned v1 = feat16[(e1 & 0xFFFFu) * 32 + c];
            unsigned v2 = feat16[(e2 & 0xFFFFu) * 32 + c];
            unsigned v3 = feat16[(e3 & 0xFFFFu) * 32 + c];
            float w0 = __uint_as_float(e0 & 0xFFFF0000u);
            float w1 = __uint_as_float(e1 & 0xFFFF0000u);
            float w2 = __uint_as_float(e2 & 0xFFFF0000u);
            float w3 = __uint_as_float(e3 & 0xFFFF0000u);
            ax = fmaf(w0, __uint_as_float(v0 << 16), ax);
            ay = fmaf(w0, __uint_as_float(v0 & 0xFFFF0000u), ay);
            bx = fmaf(w1, __uint_as_float(v1 << 16), bx);
            by = fmaf(w1, __uint_as_float(v1 & 0xFFFF0000u), by);
            ax = fmaf(w2, __uint_as_float(v2 << 16), ax);
            ay = fmaf(w2, __uint_as_float(v2 & 0xFFFF0000u), ay);
            bx = fmaf(w3, __uint_as_float(v3 << 16), bx);
            by = fmaf(w3, __uint_as_float(v3 & 0xFFFF0000u), by);
            l += (w0 + w1) + (w2 + w3);
        }
        for (; tt < m; tt += 2) {            // tail (odd edge covered by zero pad)
            unsigned e0 = __shfl(u, tt + h);
            unsigned v0 = feat16[(e0 & 0xFFFFu) * 32 + c];
            float w0 = __uint_as_float(e0 & 0xFFFF0000u);
            ax = fmaf(w0, __uint_as_float(v0 << 16), ax);
            ay = fmaf(w0, __uint_as_float(v0 & 0xFFFF0000u), ay);
            l += w0;
        }
        ax += bx; ay += by;
        ax += __shfl_xor(ax, 32);            // combine the two half-waves
        ay += __shfl_xor(ay, 32);
        l  += __shfl_xor(l, 32);
        float inv = 1.f / (l + 1e-9f);

        if (h == 0) { pl[2 * c] = ax; pl[2 * c + 1] = ay; }  // raw g, lane=dim
        float acc1 = l * b1l;                // wave-private LDS; DS in-order per wave
        #pragma unroll
        for (int k4 = 0; k4 < 16; ++k4) {
            float4 w = wrow1[k4];
            float4 g = *(const float4*)&pl[k4 * 4];
            acc1 = fmaf(g.x, w.x, acc1);
            acc1 = fmaf(g.y, w.y, acc1);
            acc1 = fmaf(g.z, w.z, acc1);
            acc1 = fmaf(g.w, w.w, acc1);
        }
        float hn = acc1 * inv;
        float fd = feat[n * DD + lane];
        pl[lane] = fd * hn;                  // stage p (all GEMV1 reads already issued)
        float acc2 = b2l;
        #pragma unroll
        for (int k4 = 0; k4 < 16; ++k4) {
            float4 w = wrow2[k4];
            float4 pk = *(const float4*)&pl[k4 * 4];
            acc2 = fmaf(pk.x, w.x, acc2);
            acc2 = fmaf(pk.y, w.y, acc2);
            acc2 = fmaf(pk.z, w.z, acc2);
            acc2 = fmaf(pk.w, w.w, acc2);
        }
        out[n * DD + lane] = lrelu(fd + hn + acc2);
    }
}

extern "C" void kernel_launch(void* const* d_in, const int* in_sizes, int n_in,
                              void* d_out, int out_size, void* d_ws, size_t ws_size,
                              hipStream_t stream) {
    const int*   indices = (const int*)d_in[0];    // (2,E)
    const float* feat    = (const float*)d_in[1];  // (N,64)
    const int*   etype   = (const int*)d_in[2];    // (E,)
    const float* W1      = (const float*)d_in[4];
    const float* W1b     = (const float*)d_in[5];
    const float* W2      = (const float*)d_in[6];
    const float* W2b     = (const float*)d_in[7];
    const float* Watt    = (const float*)d_in[8];
    const float* Wattb   = (const float*)d_in[9];
    const float* a       = (const float*)d_in[10]; // (128,1)

    const int E = in_sizes[2];
    const int N = in_sizes[1] / DD;                // 50000 (< 65536: src fits in 16 bits)
    const int* src = indices;
    const int* dst = indices + E;
    const int pcap = E / PART + 8192;              // mean + ~25 sigma slack

    float* ws = (float*)d_ws;
    float*    s_src  = ws;                         // N
    float*    s_dst  = s_src + N;                  // N
    int*      cnt    = (int*)(s_dst + N);          // N
    int*      gcur   = cnt + N;                    // 8 (pad to 16)
    unsigned* feat16 = (unsigned*)(gcur + 16);     // N*32 uints (bf16 pairs)
    unsigned* wpack  = feat16 + (size_t)N * 32;    // N*64 uints (fixed-CAP edge rows)
    uint2*    plist  = (uint2*)(wpack + (size_t)N * 64);  // 8*pcap uint2

    k_node1<<<(N + 15) / 16, 256, 0, stream>>>(feat, Watt, Wattb, a,
                                               s_src, s_dst, feat16, cnt, gcur, N);
    k_bucketA<<<2048, 256, 0, stream>>>(src, dst, etype, s_src, s_dst,
                                        gcur, plist, pcap, E);
    k_bucketB<<<2048, 256, 0, stream>>>(gcur, plist, pcap, cnt, wpack);
    k_gather<<<1024, 256, 0, stream>>>(feat, feat16, W1, W1b, W2, W2b,
                                       cnt, wpack, (float*)d_out, N);
}

// Round 9
// 234.341 us; speedup vs baseline: 1.1268x; 1.1268x over previous
//
#include <hip/hip_runtime.h>
#include <math.h>

#define DD 64
#define WSTR 68          // weight-row LDS stride: 16B-aligned, even bank spread
#define NEG_SLOPE 0.2f
#define SCALING 0.125f   // 1/sqrt(64)
#define CAP 64           // per-node slot capacity; deg~Bin(1.25M,1/50k), P(>64)~3e-15
#define CN 25            // coarse bins = dst>>11 (2048 nodes each), max 49999>>11 = 24
#define FPC 32           // fine bins per coarse (64 nodes each)
#define FINE 64          // nodes per fine partition
#define CAPA 53248       // per-coarse record capacity (mean 51200, +9 sigma)
#define CAPBG 2048       // per-fine record capacity (mean 1600, +11 sigma)
#define CAPL 128         // LDS staging per bin per chunk

__device__ __forceinline__ float lrelu(float x) { return x >= 0.0f ? x : NEG_SLOPE * x; }

__device__ __forceinline__ unsigned bf16_rne(float f) {   // round-to-nearest-even bf16 bits
    unsigned u = __float_as_uint(f);
    u += 0x7FFFu + ((u >> 16) & 1u);
    return u >> 16;
}

__device__ __forceinline__ float bfly_sum64(float v) {
    #pragma unroll
    for (int off = 1; off < 64; off <<= 1) v += __shfl_xor(v, off);
    return v;
}

// ---- K1: fused prep (wave0 folds Watt/a -> v1,v2,c1,c2) + per-node attention
//          scalars + bf16 feature cast; block 0 zeroes the bin cursors.
__global__ __launch_bounds__(256) void k_node1(
        const float* __restrict__ feat, const float* __restrict__ Watt,
        const float* __restrict__ Wattb, const float* __restrict__ a,
        float* __restrict__ s_src, float* __restrict__ s_dst,
        unsigned* __restrict__ feat16, int* __restrict__ gcur, int N) {
    __shared__ float v1s[DD], v2s[DD], csh[2];
    int t = threadIdx.x;
    if (blockIdx.x == 0) for (int i = t; i < 32 + CN * FPC; i += 256) gcur[i] = 0;
    if (t < 64) {                             // wave 0 recomputes the tiny fold
        float s1 = 0.f, s2 = 0.f;
        for (int d = 0; d < DD; ++d) {
            float w = Watt[d * DD + t];
            s1 = fmaf(w, a[d], s1);
            s2 = fmaf(w, a[DD + d], s2);
        }
        v1s[t] = s1; v2s[t] = s2;
        float b = Wattb[t];
        float p1 = bfly_sum64(b * a[t]);
        float p2 = bfly_sum64(b * a[DD + t]);
        if (t == 0) { csh[0] = p1; csh[1] = p2; }
    }
    __syncthreads();
    int lane = t & 63, wslot = t >> 6;
    float v1l = v1s[lane], v2l = v2s[lane], c1 = csh[0], c2 = csh[1];
    int n0 = (blockIdx.x * 4 + wslot) * 4;    // quad of nodes per wave
    if (n0 >= N) return;

    float fd[4], p1[4], p2[4];
    #pragma unroll
    for (int i = 0; i < 4; ++i) {
        int n = n0 + i;
        fd[i] = (n < N) ? feat[n * DD + lane] : 0.f;
        p1[i] = fd[i] * v1l;
        p2[i] = fd[i] * v2l;
    }
    #pragma unroll
    for (int off = 1; off < 64; off <<= 1) {  // 8 interleaved butterfly chains
        #pragma unroll
        for (int i = 0; i < 4; ++i) {
            p1[i] += __shfl_xor(p1[i], off);
            p2[i] += __shfl_xor(p2[i], off);
        }
    }
    #pragma unroll
    for (int i = 0; i < 4; ++i) {
        int n = n0 + i;
        unsigned me = bf16_rne(fd[i]);
        unsigned pair = me | (__shfl_down(me, 1) << 16);  // even lanes: packed (2c,2c+1)
        unsigned v = __shfl(pair, 2 * lane);              // lane c<32 <- lane 2c
        if (n < N) {
            if (lane < 32) feat16[n * 32 + lane] = v;
            if (lane == 0) { s_src[n] = p1[i] + c1; s_dst[n] = p2[i] + c2; }
        }
    }
}

// ---- K2a: coarse binning. One 1024-edge chunk per block; records (w|src, dst)
//           staged in 25 LDS bins, flushed with coalesced appends to plistA.
//           ALL global writes coalesced (scattered spill path ~never taken).
__global__ __launch_bounds__(256) void k_binA(
        const int* __restrict__ src, const int* __restrict__ dst,
        const int* __restrict__ et,
        const float* __restrict__ s_src, const float* __restrict__ s_dst,
        int* __restrict__ gcurA, uint2* __restrict__ plistA, int E) {
    __shared__ uint2 buf[CN][CAPL];
    __shared__ int cntL[CN], baseL[CN];
    int t = threadIdx.x;
    if (t < CN) cntL[t] = 0;
    __syncthreads();
    int cbase = blockIdx.x * 1024;
    #pragma unroll
    for (int k = 0; k < 4; ++k) {
        int i = cbase + k * 256 + t;
        if (i < E) {
            int d = dst[i], s = src[i];
            float e = s_src[s] + s_dst[d] + (et[i] == 0 ? 5.0f : 0.0f);
            float w = __expf(lrelu(e * SCALING));
            uint2 rec = make_uint2((bf16_rne(w) << 16) | (unsigned)s, (unsigned)d);
            int p = d >> 11;
            int pos = atomicAdd(&cntL[p], 1);
            if (pos < CAPL) buf[p][pos] = rec;
            else {                            // ~never (mean 41/bin, cap 128)
                int g = atomicAdd(&gcurA[p], 1);
                if (g < CAPA) plistA[(size_t)p * CAPA + g] = rec;
            }
        }
    }
    __syncthreads();
    if (t < CN) {
        int nr = cntL[t]; if (nr > CAPL) nr = CAPL;
        baseL[t] = atomicAdd(&gcurA[t], nr);
    }
    __syncthreads();
    #pragma unroll 1
    for (int pp = 0; pp < CN; ++pp) {
        int nr = cntL[pp]; if (nr > CAPL) nr = CAPL;
        int gb = baseL[pp];
        for (int j = t; j < nr; j += 256)
            if (gb + j < CAPA) plistA[(size_t)pp * CAPA + gb + j] = buf[pp][j];
    }
}

// ---- K2b: fine binning. Block (c, slice) consumes coarse list c in 1024-record
//           chunks (coalesced reads), bins by (dst>>6)&31 into 32 LDS bins,
//           flushes coalesced to plistB[q], q = c*32 + fine.
__global__ __launch_bounds__(256) void k_binB(
        const int* __restrict__ gcurA, const uint2* __restrict__ plistA,
        int* __restrict__ gcurB, uint2* __restrict__ plistB) {
    __shared__ uint2 buf[FPC][CAPL];
    __shared__ int cntL[FPC], baseL[FPC];
    int t = threadIdx.x;
    int c = blockIdx.x >> 5, slice = blockIdx.x & 31;
    int M = gcurA[c]; if (M > CAPA) M = CAPA;
    for (int k = slice; (size_t)k * 1024 < (size_t)M; k += 32) {
        if (t < FPC) cntL[t] = 0;
        __syncthreads();
        int cb = k * 1024;
        #pragma unroll
        for (int kk = 0; kk < 4; ++kk) {
            int j = cb + kk * 256 + t;
            if (j < M) {
                uint2 rec = plistA[(size_t)c * CAPA + j];
                int p = (rec.y >> 6) & 31;
                int pos = atomicAdd(&cntL[p], 1);
                if (pos < CAPL) buf[p][pos] = rec;
                else {
                    int q = c * FPC + p;
                    int g = atomicAdd(&gcurB[q], 1);
                    if (g < CAPBG) plistB[(size_t)q * CAPBG + g] = rec;
                }
            }
        }
        __syncthreads();
        if (t < FPC) {
            int nr = cntL[t]; if (nr > CAPL) nr = CAPL;
            baseL[t] = atomicAdd(&gcurB[c * FPC + t], nr);
        }
        __syncthreads();
        #pragma unroll 1
        for (int pp = 0; pp < FPC; ++pp) {
            int nr = cntL[pp]; if (nr > CAPL) nr = CAPL;
            int gb = baseL[pp];
            int q = c * FPC + pp;
            for (int j = t; j < nr; j += 256)
                if (gb + j < CAPBG) plistB[(size_t)q * CAPBG + gb + j] = buf[pp][j];
        }
        __syncthreads();
    }
}

// ---- K3: fused assemble+gather. Block q: read partition q's records
//          (coalesced), assemble 64 node rows in LDS, then per-wave gather
//          g = sum_j w_j*feat[src_j] (half-wave rows, ILP-4) and the two
//          LDS GEMVs: h_neigh = (W1 g + l b1)/(l+eps),
//          out = lrelu(f + hn + (f*hn)@W2^T + b2). wpack never hits global.
__global__ __launch_bounds__(256) void k_gatherB(
        const float* __restrict__ feat, const unsigned* __restrict__ feat16,
        const float* __restrict__ W1, const float* __restrict__ W1b,
        const float* __restrict__ W2, const float* __restrict__ W2b,
        const int* __restrict__ gcurB, const uint2* __restrict__ plistB,
        float* __restrict__ out, int N) {
    __shared__ float W1p[DD * WSTR], W2p[DD * WSTR];
    __shared__ unsigned rows[FINE][CAP];
    __shared__ int lcnt[FINE];
    __shared__ float plds[4][DD];
    int t = threadIdx.x;
    for (int i = t; i < DD * DD; i += 256) {
        int d = i >> 6, k = i & 63;
        W1p[d * WSTR + k] = W1[i];
        W2p[d * WSTR + k] = W2[i];
    }
    if (t < FINE) lcnt[t] = 0;
    __syncthreads();
    int q = blockIdx.x;
    int M = gcurB[q]; if (M > CAPBG) M = CAPBG;
    for (int j = t; j < M; j += 256) {        // coalesced record reads
        uint2 r = plistB[(size_t)q * CAPBG + j];
        int dl = (int)(r.y & 63u);
        int slot = atomicAdd(&lcnt[dl], 1);
        if (slot < CAP) rows[dl][slot] = r.x; // LDS scatter: cheap
    }
    __syncthreads();
    int lane = t & 63, wslot = t >> 6;
    int c = lane & 31, h = lane >> 5;         // half-wave id: processes edges tt+h
    float b1l = W1b[lane], b2l = W2b[lane];
    const float4* wrow1 = (const float4*)&W1p[lane * WSTR];
    const float4* wrow2 = (const float4*)&W2p[lane * WSTR];
    float* pl = plds[wslot];
    for (int i = 0; i < 16; ++i) {            // 16 nodes per wave
        int nl = wslot * 16 + i;
        int n = q * FINE + nl;
        if (n >= N) break;
        int m = lcnt[nl]; if (m > CAP) m = CAP;
        unsigned u = rows[nl][lane];          // stride-1: 2-way bank alias (free)
        if (lane >= m) u = 0;                 // pad: w=0, src=0

        float ax = 0.f, ay = 0.f, bx = 0.f, by = 0.f, l = 0.f;
        int tt = 0;
        for (; tt + 8 <= m; tt += 8) {        // 8 edges in flight (4 per half-wave)
            unsigned e0 = __shfl(u, tt + h);
            unsigned e1 = __shfl(u, tt + 2 + h);
            unsigned e2 = __shfl(u, tt + 4 + h);
            unsigned e3 = __shfl(u, tt + 6 + h);
            unsigned v0 = feat16[(e0 & 0xFFFFu) * 32 + c];
            unsigned v1 = feat16[(e1 & 0xFFFFu) * 32 + c];
            unsigned v2 = feat16[(e2 & 0xFFFFu) * 32 + c];
            unsigned v3 = feat16[(e3 & 0xFFFFu) * 32 + c];
            float w0 = __uint_as_float(e0 & 0xFFFF0000u);
            float w1 = __uint_as_float(e1 & 0xFFFF0000u);
            float w2 = __uint_as_float(e2 & 0xFFFF0000u);
            float w3 = __uint_as_float(e3 & 0xFFFF0000u);
            ax = fmaf(w0, __uint_as_float(v0 << 16), ax);
            ay = fmaf(w0, __uint_as_float(v0 & 0xFFFF0000u), ay);
            bx = fmaf(w1, __uint_as_float(v1 << 16), bx);
            by = fmaf(w1, __uint_as_float(v1 & 0xFFFF0000u), by);
            ax = fmaf(w2, __uint_as_float(v2 << 16), ax);
            ay = fmaf(w2, __uint_as_float(v2 & 0xFFFF0000u), ay);
            bx = fmaf(w3, __uint_as_float(v3 << 16), bx);
            by = fmaf(w3, __uint_as_float(v3 & 0xFFFF0000u), by);
            l += (w0 + w1) + (w2 + w3);
        }
        for (; tt < m; tt += 2) {             // tail (odd edge covered by zero pad)
            unsigned e0 = __shfl(u, tt + h);
            unsigned v0 = feat16[(e0 & 0xFFFFu) * 32 + c];
            float w0 = __uint_as_float(e0 & 0xFFFF0000u);
            ax = fmaf(w0, __uint_as_float(v0 << 16), ax);
            ay = fmaf(w0, __uint_as_float(v0 & 0xFFFF0000u), ay);
            l += w0;
        }
        ax += bx; ay += by;
        ax += __shfl_xor(ax, 32);             // combine the two half-waves
        ay += __shfl_xor(ay, 32);
        l  += __shfl_xor(l, 32);
        float inv = 1.f / (l + 1e-9f);

        if (h == 0) { pl[2 * c] = ax; pl[2 * c + 1] = ay; }  // raw g, lane=dim
        float acc1 = l * b1l;                 // wave-private LDS; DS in-order per wave
        #pragma unroll
        for (int k4 = 0; k4 < 16; ++k4) {
            float4 w = wrow1[k4];
            float4 g = *(const float4*)&pl[k4 * 4];
            acc1 = fmaf(g.x, w.x, acc1);
            acc1 = fmaf(g.y, w.y, acc1);
            acc1 = fmaf(g.z, w.z, acc1);
            acc1 = fmaf(g.w, w.w, acc1);
        }
        float hn = acc1 * inv;
        float fd = feat[n * DD + lane];
        pl[lane] = fd * hn;                   // stage p (GEMV1 reads already issued)
        float acc2 = b2l;
        #pragma unroll
        for (int k4 = 0; k4 < 16; ++k4) {
            float4 w = wrow2[k4];
            float4 pk = *(const float4*)&pl[k4 * 4];
            acc2 = fmaf(pk.x, w.x, acc2);
            acc2 = fmaf(pk.y, w.y, acc2);
            acc2 = fmaf(pk.z, w.z, acc2);
            acc2 = fmaf(pk.w, w.w, acc2);
        }
        out[n * DD + lane] = lrelu(fd + hn + acc2);
    }
}

extern "C" void kernel_launch(void* const* d_in, const int* in_sizes, int n_in,
                              void* d_out, int out_size, void* d_ws, size_t ws_size,
                              hipStream_t stream) {
    const int*   indices = (const int*)d_in[0];    // (2,E)
    const float* feat    = (const float*)d_in[1];  // (N,64)
    const int*   etype   = (const int*)d_in[2];    // (E,)
    const float* W1      = (const float*)d_in[4];
    const float* W1b     = (const float*)d_in[5];
    const float* W2      = (const float*)d_in[6];
    const float* W2b     = (const float*)d_in[7];
    const float* Watt    = (const float*)d_in[8];
    const float* Wattb   = (const float*)d_in[9];
    const float* a       = (const float*)d_in[10]; // (128,1)

    const int E = in_sizes[2];
    const int N = in_sizes[1] / DD;                // 50000 (< 65536: src fits in 16 bits)
    const int* src = indices;
    const int* dst = indices + E;
    const int NPART = (N + FINE - 1) / FINE;       // 782 fine partitions

    float* ws = (float*)d_ws;
    float*    s_src  = ws;                            // N
    float*    s_dst  = s_src + N;                     // N
    int*      gcur   = (int*)(s_dst + N);             // 32 + 800 cursors (pad 1024)
    int*      gcurA  = gcur;                          // [0..24]
    int*      gcurB  = gcur + 32;                     // [0..799]
    unsigned* feat16 = (unsigned*)(gcur + 1024);      // N*32 uints (bf16 pairs)
    uint2*    plistA = (uint2*)(feat16 + (size_t)N * 32);      // 25*CAPA uint2
    uint2*    plistB = plistA + (size_t)CN * CAPA;             // 800*CAPBG uint2

    k_node1<<<(N + 15) / 16, 256, 0, stream>>>(feat, Watt, Wattb, a,
                                               s_src, s_dst, feat16, gcur, N);
    k_binA<<<(E + 1023) / 1024, 256, 0, stream>>>(src, dst, etype, s_src, s_dst,
                                                  gcurA, plistA, E);
    k_binB<<<CN * 32, 256, 0, stream>>>(gcurA, plistA, gcurB, plistB);
    k_gatherB<<<NPART, 256, 0, stream>>>(feat, feat16, W1, W1b, W2, W2b,
                                         gcurB, plistB, (float*)d_out, N);
}